// Round 11
// baseline (21.206 us; speedup 1.0000x reference)
//
#include <hip/hip_runtime.h>
#include <math.h>

#define NG  8
#define DH  8
#define NCP 4     // channel pairs
#define KS  7
#define PAD 3
#define TH  16    // tile rows
#define TW  32    // tile cols
#define OW  2     // outputs per thread along W
#define TPH 22    // padded tile rows
#define RSTW 42   // LDS row stride in h2-words (38 cols + 4 pad; 42: wave rows {r,r+1,r+4,r+5} -> distinct bank offsets)
#define PLW  (TPH * RSTW)   // 924 words per cp-plane
#define CH  64
#define HH  64
#define WW  64

typedef __fp16 h2v __attribute__((ext_vector_type(2)));
typedef __fp16 h4v __attribute__((ext_vector_type(4)));

__device__ __forceinline__ int imin(int a, int b) { return a < b ? a : b; }
__device__ __forceinline__ int imax(int a, int b) { return a > b ? a : b; }

__global__ __launch_bounds__(512, 2)   // empirical VGPR cap = 256/2 = 128 -> 4 waves/SIMD
void saconv_kernel(const float* __restrict__ x,
                   const float* __restrict__ wq,
                   const float* __restrict__ wk,
                   const float* __restrict__ wv,
                   const float* __restrict__ relh,
                   const float* __restrict__ relw,
                   float* __restrict__ out) {
  // xs2[cp*PLW + row*RSTW + col] = h2( x[b,g*8+2cp,row',col'], x[b,g*8+2cp+1,row',col'] )
  __shared__ h2v xs2[NCP * PLW];        // 14.8 KB
  __shared__ float swq[DH * DH];
  __shared__ float swk[DH * DH];
  __shared__ float swv[DH * DH];
  __shared__ float srel[DH * KS];

  const int tx    = threadIdx.x;        // 0..15 (pair of output columns)
  const int ihalf = threadIdx.y;        // 0..1  (window-row half; partner = lane^16)
  const int ty    = threadIdx.z;        // 0..15 (output row)
  const int tid   = tx + 16 * ihalf + 32 * ty;   // 0..511
  const int bz  = blockIdx.z;
  const int b   = bz >> 3;
  const int g   = bz & 7;
  const int h0  = blockIdx.y * TH;
  const int w0  = blockIdx.x * TW;

  // ---- stage weights + rel table ----
  if (tid < DH * DH) swq[tid] = wq[g * DH * DH + tid];
  else if (tid < 2 * DH * DH) swk[tid - 64] = wk[g * DH * DH + tid - 64];
  else if (tid < 3 * DH * DH) swv[tid - 128] = wv[g * DH * DH + tid - 128];
  else if (tid < 3 * DH * DH + DH * KS) {
    int t2 = tid - 192;
    int c = t2 / KS, t = t2 - c * KS;
    int gc = g * DH + c;
    srel[t2] = (g < 4) ? relh[gc * KS + t] : relw[(gc - 32) * KS + t];
  }

  // ---- stage zero-padded x tile as f16 channel-pairs (b64 = 2 cols) ----
  const float* xb = x + (size_t)(b * CH + g * DH) * (HH * WW);
  const int NCHK = NCP * TPH * 19;      // 1672 b64 chunks (cols 0..37)
  #pragma unroll
  for (int kk = 0; kk < 4; kk++) {
    int f = tid + kk * 512;
    if (kk < 3 || f < NCHK) {
      int cp  = f / (TPH * 19);
      int r   = f - cp * (TPH * 19);
      int row = r / 19;
      int cc  = r - row * 19;
      int yy  = h0 + row - PAD;
      int cy  = imin(imax(yy, 0), HH - 1);
      bool yok = (yy >= 0) & (yy < HH);
      const float* p0 = xb + ((size_t)(2 * cp) * HH + cy) * WW;
      float v0[2], v1[2];
      #pragma unroll
      for (int e = 0; e < 2; e++) {
        int xx = w0 + 2 * cc + e - PAD;
        int cx = imin(imax(xx, 0), WW - 1);
        bool inb = yok & (xx >= 0) & (xx < WW);
        float a0 = p0[cx];
        float a1 = p0[HH * WW + cx];
        v0[e] = inb ? a0 : 0.0f;
        v1[e] = inb ? a1 : 0.0f;
      }
      h2v pk0 = __builtin_amdgcn_cvt_pkrtz(v0[0], v1[0]);
      h2v pk1 = __builtin_amdgcn_cvt_pkrtz(v0[1], v1[1]);
      h4v w4 = { pk0.x, pk0.y, pk1.x, pk1.y };
      *(h4v*)&xs2[cp * PLW + row * RSTW + 2 * cc] = w4;
    }
  }
  __syncthreads();

  // ---- preamble: q, fold qk (packed f16, log2-domain), rq (log2-domain) ----
  const float scale = 0.35355339059327373f;   // sqrt(1/8)
  const float L2E   = 1.4426950408889634f;
  h2v  qkh[OW][NCP];
  float rq[OW][8];                            // [7] = 0 (static-index headroom)
  {
    float xc[OW][DH];
    #pragma unroll
    for (int o = 0; o < OW; o++)
      #pragma unroll
      for (int cp = 0; cp < NCP; cp++) {
        h2v wv2 = xs2[cp * PLW + (ty + PAD) * RSTW + (2 * tx + o + PAD)];
        xc[o][2 * cp]     = (float)wv2.x;
        xc[o][2 * cp + 1] = (float)wv2.y;
      }
    float q_[OW][DH];
    #pragma unroll
    for (int o = 0; o < OW; o++)
      #pragma unroll
      for (int c = 0; c < DH; c++) {
        float a = 0.f;
        #pragma unroll
        for (int ci = 0; ci < DH; ci++)
          a = fmaf(swq[c * DH + ci], xc[o][ci], a);
        q_[o][c] = a;
      }
    #pragma unroll
    for (int o = 0; o < OW; o++)
      #pragma unroll
      for (int cp = 0; cp < NCP; cp++) {
        float a0 = 0.f, a1 = 0.f;
        #pragma unroll
        for (int c = 0; c < DH; c++) {
          a0 = fmaf(q_[o][c], swk[c * DH + 2 * cp], a0);
          a1 = fmaf(q_[o][c], swk[c * DH + 2 * cp + 1], a1);
        }
        qkh[o][cp] = __builtin_amdgcn_cvt_pkrtz(a0 * (scale * L2E), a1 * (scale * L2E));
      }
    #pragma unroll
    for (int o = 0; o < OW; o++) {
      #pragma unroll
      for (int t = 0; t < KS; t++) {
        float a = 0.f;
        #pragma unroll
        for (int c = 0; c < DH; c++)
          a = fmaf(q_[o][c], srel[c * KS + t], a);
        rq[o][t] = a * (scale * L2E);
      }
      rq[o][7] = 0.f;
    }
  }

  // ---- window loop, i-split: ihalf=0 -> rows 0..3, ihalf=1 -> rows 4..6 ----
  const bool useI = (g < 4);
  float s[OW] = {0.f, 0.f};
  float xa[OW][DH];
  #pragma unroll
  for (int o = 0; o < OW; o++)
    #pragma unroll
    for (int ci = 0; ci < DH; ci++) xa[o][ci] = 0.f;

  #pragma unroll
  for (int u = 0; u < 4; u++) {
    if (u < 3 || ihalf == 0) {          // ihalf=1 has only 3 rows
      const int row = ty + 4 * ihalf + u;
      const int wbase = row * RSTW + 2 * tx;
      h2v xw[NCP][8];
      #pragma unroll
      for (int cp = 0; cp < NCP; cp++) {
        const h4v* bp = (const h4v*)&xs2[cp * PLW + wbase];
        h4v r0 = bp[0], r1 = bp[1], r2 = bp[2], r3 = bp[3];
        xw[cp][0] = __builtin_shufflevector(r0, r0, 0, 1);
        xw[cp][1] = __builtin_shufflevector(r0, r0, 2, 3);
        xw[cp][2] = __builtin_shufflevector(r1, r1, 0, 1);
        xw[cp][3] = __builtin_shufflevector(r1, r1, 2, 3);
        xw[cp][4] = __builtin_shufflevector(r2, r2, 0, 1);
        xw[cp][5] = __builtin_shufflevector(r2, r2, 2, 3);
        xw[cp][6] = __builtin_shufflevector(r3, r3, 0, 1);
        xw[cp][7] = __builtin_shufflevector(r3, r3, 2, 3);
      }

      #pragma unroll
      for (int o = 0; o < OW; o++) {
        float e[KS];
        float se = 0.f;
        #pragma unroll
        for (int j = 0; j < KS; j++) {
          // rel: static indices in both arms (u compile-time); u=3&&ihalf=1 is dead
          float d = useI ? (ihalf ? rq[o][u + 4] : rq[o][u]) : rq[o][j];
          #pragma unroll
          for (int cp = 0; cp < NCP; cp++)
            d = __builtin_amdgcn_fdot2(qkh[o][cp], xw[cp][o + j], d, false);
          e[j] = exp2f(d);
          se += e[j];
        }
        s[o] += se;
        #pragma unroll
        for (int cp = 0; cp < NCP; cp++) {
          float a0 = xa[o][2 * cp];
          float a1 = xa[o][2 * cp + 1];
          #pragma unroll
          for (int j = 0; j < KS; j++) {
            a0 = fmaf(e[j], (float)xw[cp][o + j].x, a0);   // v_fma_mix_f32
            a1 = fmaf(e[j], (float)xw[cp][o + j].y, a1);
          }
          xa[o][2 * cp]     = a0;
          xa[o][2 * cp + 1] = a1;
        }
      }
    }
  }

  // ---- combine i-halves (single end exchange; exact, no max-shift) ----
  float xav[OW][DH];
  float inv[OW];
  #pragma unroll
  for (int o = 0; o < OW; o++) {
    float st = s[o] + __shfl_xor(s[o], 16, 64);
    inv[o] = 1.0f / st;
  }
  #pragma unroll
  for (int o = 0; o < OW; o++)
    #pragma unroll
    for (int ci = 0; ci < DH; ci++) {
      float t_ = xa[o][ci];
      xav[o][ci] = (t_ + __shfl_xor(t_, 16, 64)) * inv[o];
    }

  // ---- epilogue: out = Wv * xav; each half stores 4 channels, static indices ----
  const int h = h0 + ty;
  const int wbase = w0 + 2 * tx;
  float* ob = out + (((size_t)(b * CH + g * DH) * HH + h) * WW + wbase);
  if (ihalf == 0) {
    #pragma unroll
    for (int n = 0; n < 4; n++) {
      float a0 = 0.f, a1 = 0.f;
      #pragma unroll
      for (int ci = 0; ci < DH; ci++) {
        a0 = fmaf(swv[n * DH + ci], xav[0][ci], a0);
        a1 = fmaf(swv[n * DH + ci], xav[1][ci], a1);
      }
      *(float2*)(ob + (size_t)n * (HH * WW)) = make_float2(a0, a1);
    }
  } else {
    #pragma unroll
    for (int n = 0; n < 4; n++) {
      float a0 = 0.f, a1 = 0.f;
      #pragma unroll
      for (int ci = 0; ci < DH; ci++) {
        a0 = fmaf(swv[(4 + n) * DH + ci], xav[0][ci], a0);
        a1 = fmaf(swv[(4 + n) * DH + ci], xav[1][ci], a1);
      }
      *(float2*)(ob + (size_t)(4 + n) * (HH * WW)) = make_float2(a0, a1);
    }
  }
}

extern "C" void kernel_launch(void* const* d_in, const int* in_sizes, int n_in,
                              void* d_out, int out_size, void* d_ws, size_t ws_size,
                              hipStream_t stream) {
  const float* x    = (const float*)d_in[0];
  // d_in[1] = r, unused by the reference computation
  const float* wq   = (const float*)d_in[2];
  const float* wk   = (const float*)d_in[3];
  const float* wv   = (const float*)d_in[4];
  const float* relh = (const float*)d_in[5];
  const float* relw = (const float*)d_in[6];
  float* out = (float*)d_out;

  const int B = in_sizes[0] / (CH * HH * WW);   // 8
  dim3 grid(WW / TW, HH / TH, B * NG);          // 2 x 4 x 64 = 512 blocks
  dim3 block(16, 2, 16);                        // 512 threads = 8 waves
  saconv_kernel<<<grid, block, 0, stream>>>(x, wq, wk, wv, relh, relw, out);
}

// Round 12
// 17.593 us; speedup vs baseline: 1.2054x; 1.2054x over previous
//
#include <hip/hip_runtime.h>
#include <math.h>

#define NG  8
#define DH  8
#define NCP 4     // channel pairs
#define KS  7
#define PAD 3
#define TH  16    // tile rows
#define TW  32    // tile cols
#define OW  2     // outputs per thread along W
#define TPH 22    // padded tile rows
#define RSTW 40   // LDS row stride in h2-words (38 cols + 2 pad)
#define PLW  (TPH * RSTW)   // 880 words per cp-plane
#define CH  64
#define HH  64
#define WW  64

typedef __fp16 h2v __attribute__((ext_vector_type(2)));
typedef __fp16 h4v __attribute__((ext_vector_type(4)));

#if __has_builtin(__builtin_amdgcn_exp2f)
#define EXP2(x) __builtin_amdgcn_exp2f(x)
#else
#define EXP2(x) exp2f(x)
#endif

__device__ __forceinline__ int imin(int a, int b) { return a < b ? a : b; }
__device__ __forceinline__ int imax(int a, int b) { return a > b ? a : b; }

__global__ __launch_bounds__(256, 2)   // cap 128 VGPR -> guarantee 2 blocks/CU (2 waves/SIMD)
void saconv_kernel(const float* __restrict__ x,
                   const float* __restrict__ wq,
                   const float* __restrict__ wk,
                   const float* __restrict__ wv,
                   const float* __restrict__ relh,
                   const float* __restrict__ relw,
                   float* __restrict__ out) {
  // xs2[cp*PLW + row*RSTW + col] = h2( x[b,g*8+2cp,row',col'], x[b,g*8+2cp+1,row',col'] )
  __shared__ h2v xs2[NCP * PLW];        // 14.1 KB
  __shared__ float swq[DH * DH];
  __shared__ float swk[DH * DH];
  __shared__ float swv[DH * DH];
  __shared__ float srel[DH * KS];

  const int tx  = threadIdx.x;          // 0..15 (pair of output columns)
  const int ty  = threadIdx.y;          // 0..15 (output row)
  const int tid = ty * 16 + tx;
  const int bz  = blockIdx.z;
  const int b   = bz >> 3;
  const int g   = bz & 7;
  const int h0  = blockIdx.y * TH;
  const int w0  = blockIdx.x * TW;

  // ---- stage weights + rel table ----
  if (tid < DH * DH) swq[tid] = wq[g * DH * DH + tid];
  else if (tid < 2 * DH * DH) swk[tid - 64] = wk[g * DH * DH + tid - 64];
  else if (tid < 3 * DH * DH) swv[tid - 128] = wv[g * DH * DH + tid - 128];
  else if (tid < 3 * DH * DH + DH * KS) {
    int t2 = tid - 192;
    int c = t2 / KS, t = t2 - c * KS;
    int gc = g * DH + c;
    srel[t2] = (g < 4) ? relh[gc * KS + t] : relw[(gc - 32) * KS + t];
  }

  // ---- stage zero-padded x tile as f16 channel-pairs (b64 = 2 cols) ----
  const float* xb = x + (size_t)(b * CH + g * DH) * (HH * WW);
  const int NCHK = NCP * TPH * 19;      // 1672 b64 chunks (cols 0..37)
  #pragma unroll
  for (int kk = 0; kk < 7; kk++) {
    int f = tid + kk * 256;
    if (f < NCHK) {
      int cp  = f / (TPH * 19);
      int r   = f - cp * (TPH * 19);
      int row = r / 19;
      int cc  = r - row * 19;
      int yy  = h0 + row - PAD;
      int cy  = imin(imax(yy, 0), HH - 1);
      bool yok = (yy >= 0) & (yy < HH);
      const float* p0 = xb + ((size_t)(2 * cp) * HH + cy) * WW;
      float v0[2], v1[2];
      #pragma unroll
      for (int e = 0; e < 2; e++) {
        int xx = w0 + 2 * cc + e - PAD;
        int cx = imin(imax(xx, 0), WW - 1);
        bool inb = yok & (xx >= 0) & (xx < WW);
        float a0 = p0[cx];
        float a1 = p0[HH * WW + cx];
        v0[e] = inb ? a0 : 0.0f;
        v1[e] = inb ? a1 : 0.0f;
      }
      h2v pk0 = __builtin_amdgcn_cvt_pkrtz(v0[0], v1[0]);   // col 2cc: (ch lo, ch hi)
      h2v pk1 = __builtin_amdgcn_cvt_pkrtz(v0[1], v1[1]);   // col 2cc+1
      h4v w4 = { pk0.x, pk0.y, pk1.x, pk1.y };
      *(h4v*)&xs2[cp * PLW + row * RSTW + 2 * cc] = w4;
    }
  }
  __syncthreads();

  // ---- preamble: q, fold qk = scale*l2e*(Wk^T q) packed f16, rq = scale*l2e*(rel^T q) ----
  const float scale = 0.35355339059327373f;   // sqrt(1/8)
  const float L2E   = 1.4426950408889634f;
  h2v  qkh[OW][NCP];
  float rq[OW][KS];
  {
    float xc[OW][DH];
    #pragma unroll
    for (int o = 0; o < OW; o++)
      #pragma unroll
      for (int cp = 0; cp < NCP; cp++) {
        h2v wv2 = xs2[cp * PLW + (ty + PAD) * RSTW + (2 * tx + o + PAD)];
        xc[o][2 * cp]     = (float)wv2.x;
        xc[o][2 * cp + 1] = (float)wv2.y;
      }
    float q_[OW][DH];
    #pragma unroll
    for (int o = 0; o < OW; o++)
      #pragma unroll
      for (int c = 0; c < DH; c++) {
        float a = 0.f;
        #pragma unroll
        for (int ci = 0; ci < DH; ci++)
          a = fmaf(swq[c * DH + ci], xc[o][ci], a);
        q_[o][c] = a;
      }
    #pragma unroll
    for (int o = 0; o < OW; o++)
      #pragma unroll
      for (int cp = 0; cp < NCP; cp++) {
        float a0 = 0.f, a1 = 0.f;
        #pragma unroll
        for (int c = 0; c < DH; c++) {
          a0 = fmaf(q_[o][c], swk[c * DH + 2 * cp], a0);
          a1 = fmaf(q_[o][c], swk[c * DH + 2 * cp + 1], a1);
        }
        qkh[o][cp] = __builtin_amdgcn_cvt_pkrtz(a0 * (scale * L2E), a1 * (scale * L2E));
      }
    #pragma unroll
    for (int o = 0; o < OW; o++)
      #pragma unroll
      for (int t = 0; t < KS; t++) {
        float a = 0.f;
        #pragma unroll
        for (int c = 0; c < DH; c++)
          a = fmaf(q_[o][c], srel[c * KS + t], a);
        rq[o][t] = a * (scale * L2E);
      }
  }

  // ---- window loop: fdot2 logits (base-2), raw v_exp_f32, fma_mix accumulation ----
  const bool useI = (g < 4);

  float s[OW], xa[OW][DH];
  #pragma unroll
  for (int o = 0; o < OW; o++) {
    s[o] = 0.f;
    #pragma unroll
    for (int ci = 0; ci < DH; ci++) xa[o][ci] = 0.f;
  }

  #pragma unroll
  for (int i = 0; i < KS; i++) {
    const int wbase = (ty + i) * RSTW + 2 * tx;
    // 8 consecutive h2-words (cols 2tx..2tx+7) per cp-plane: 4x ds_read_b64
    h2v xw[NCP][8];
    #pragma unroll
    for (int cp = 0; cp < NCP; cp++) {
      const h4v* bp = (const h4v*)&xs2[cp * PLW + wbase];
      h4v r0 = bp[0], r1 = bp[1], r2 = bp[2], r3 = bp[3];
      xw[cp][0] = __builtin_shufflevector(r0, r0, 0, 1);
      xw[cp][1] = __builtin_shufflevector(r0, r0, 2, 3);
      xw[cp][2] = __builtin_shufflevector(r1, r1, 0, 1);
      xw[cp][3] = __builtin_shufflevector(r1, r1, 2, 3);
      xw[cp][4] = __builtin_shufflevector(r2, r2, 0, 1);
      xw[cp][5] = __builtin_shufflevector(r2, r2, 2, 3);
      xw[cp][6] = __builtin_shufflevector(r3, r3, 0, 1);
      xw[cp][7] = __builtin_shufflevector(r3, r3, 2, 3);
    }

    #pragma unroll
    for (int o = 0; o < OW; o++) {
      float e[KS];
      float se = 0.f;
      #pragma unroll
      for (int j = 0; j < KS; j++) {
        float d = useI ? rq[o][i] : rq[o][j];   // log2-domain, scale pre-folded
        #pragma unroll
        for (int cp = 0; cp < NCP; cp++)
          d = __builtin_amdgcn_fdot2(qkh[o][cp], xw[cp][o + j], d, false);
        e[j] = EXP2(d);
        se += e[j];
      }
      s[o] += se;
      #pragma unroll
      for (int cp = 0; cp < NCP; cp++) {
        float a0 = xa[o][2 * cp];
        float a1 = xa[o][2 * cp + 1];
        #pragma unroll
        for (int j = 0; j < KS; j++) {
          a0 = fmaf(e[j], (float)xw[cp][o + j].x, a0);   // v_fma_mix_f32
          a1 = fmaf(e[j], (float)xw[cp][o + j].y, a1);
        }
        xa[o][2 * cp]     = a0;
        xa[o][2 * cp + 1] = a1;
      }
    }
  }

  // ---- epilogue: out = Wv * (xa / s), float2 stores ----
  #pragma unroll
  for (int o = 0; o < OW; o++) {
    float inv = 1.0f / s[o];
    #pragma unroll
    for (int ci = 0; ci < DH; ci++) xa[o][ci] *= inv;
  }

  const int h = h0 + ty;
  const int wbase = w0 + 2 * tx;
  #pragma unroll
  for (int c = 0; c < DH; c++) {
    float2 v2;
    {
      float a0 = 0.f, a1 = 0.f;
      #pragma unroll
      for (int ci = 0; ci < DH; ci++) {
        a0 = fmaf(swv[c * DH + ci], xa[0][ci], a0);
        a1 = fmaf(swv[c * DH + ci], xa[1][ci], a1);
      }
      v2.x = a0; v2.y = a1;
    }
    *(float2*)(&out[((size_t)(b * CH + g * DH + c) * HH + h) * WW + wbase]) = v2;
  }
}

extern "C" void kernel_launch(void* const* d_in, const int* in_sizes, int n_in,
                              void* d_out, int out_size, void* d_ws, size_t ws_size,
                              hipStream_t stream) {
  const float* x    = (const float*)d_in[0];
  // d_in[1] = r, unused by the reference computation
  const float* wq   = (const float*)d_in[2];
  const float* wk   = (const float*)d_in[3];
  const float* wv   = (const float*)d_in[4];
  const float* relh = (const float*)d_in[5];
  const float* relw = (const float*)d_in[6];
  float* out = (float*)d_out;

  const int B = in_sizes[0] / (CH * HH * WW);   // 8
  dim3 grid(WW / TW, HH / TH, B * NG);          // 2 x 4 x 64 = 512 blocks
  dim3 block(16, 16, 1);                        // 256 threads = 4 waves
  saconv_kernel<<<grid, block, 0, stream>>>(x, wq, wk, wv, relh, relw, out);
}